// Round 2
// baseline (888.444 us; speedup 1.0000x reference)
//
#include <hip/hip_runtime.h>
#include <cstddef>
#include <cstdint>

// Problem constants: B=2, N=2048, DIM=512, H=8, DH=64, K=32, SCALE=1/8
#define SEQ_N  2048
#define NHEAD  8
#define DHEAD  64
#define NMEM   32
#define SCALE_F 0.125f
#define NEG_INF -3.0e38f
#define LDK 72  // padded LDS row stride (ushort units) for 64-wide bf16 tiles

typedef short bf16x8 __attribute__((ext_vector_type(8)));
typedef float f32x4  __attribute__((ext_vector_type(4)));

__device__ __forceinline__ unsigned short f2bf(float f) {
  union { float f; uint32_t u; } v; v.f = f;
  uint32_t u = v.u;
  return (unsigned short)((u + 0x7fffu + ((u >> 16) & 1u)) >> 16);  // RNE
}
__device__ __forceinline__ float bf2f(unsigned short us) {
  union { uint32_t u; float f; } v; v.u = ((uint32_t)us) << 16; return v.f;
}

__device__ __forceinline__ float wred_max(float v) {
#pragma unroll
  for (int o = 32; o > 0; o >>= 1) v = fmaxf(v, __shfl_xor(v, o));
  return v;
}
__device__ __forceinline__ float wred_sum(float v) {
#pragma unroll
  for (int o = 32; o > 0; o >>= 1) v += __shfl_xor(v, o);
  return v;
}

// ---------------------------------------------------------------------------
// Generic 64x64-tile f32 GEMM, 256 threads, 4x4 microtile per thread.
// MODE 0: qb[(b,h,i,d)] = bf16(acc * SCALE)          (rows=b*2048+i, cols=h*64+d)
// MODE 1: cols 0..63 -> kb[r*64+c] bf16; cols 64..127 -> vtb[b][c-64][i] bf16
// MODE 2: Cf[r*512+c] = acc + bias[c]  (f32)
// ---------------------------------------------------------------------------
template <int MODE>
__global__ __launch_bounds__(256) void gemm64(
    const float* __restrict__ A, const float* __restrict__ Bw,
    float* __restrict__ Cf, unsigned short* __restrict__ Ck,
    unsigned short* __restrict__ Cv,
    const float* __restrict__ bias, int Kdim, int Ncols) {
  __shared__ float sA[64][17];
  __shared__ float sB[16][64];
  const int tid = threadIdx.x;
  const int tx = tid & 15, ty = tid >> 4;
  const int rowBase = blockIdx.x * 64, colBase = blockIdx.y * 64;
  float acc[4][4] = {};

  for (int k0 = 0; k0 < Kdim; k0 += 16) {
    {
      int r = tid >> 2, ks = (tid & 3) * 4;
      float4 a4 = *(const float4*)(A + (size_t)(rowBase + r) * Kdim + k0 + ks);
      sA[r][ks + 0] = a4.x; sA[r][ks + 1] = a4.y;
      sA[r][ks + 2] = a4.z; sA[r][ks + 3] = a4.w;
    }
#pragma unroll
    for (int it = 0; it < 4; ++it) {
      int kk = (tid >> 6) + it * 4, c = tid & 63;
      sB[kk][c] = Bw[(size_t)(k0 + kk) * Ncols + colBase + c];
    }
    __syncthreads();
#pragma unroll
    for (int kk = 0; kk < 16; ++kk) {
      float av[4];
#pragma unroll
      for (int u = 0; u < 4; ++u) av[u] = sA[ty * 4 + u][kk];
      float4 b4 = *(const float4*)&sB[kk][tx * 4];
#pragma unroll
      for (int u = 0; u < 4; ++u) {
        acc[u][0] += av[u] * b4.x; acc[u][1] += av[u] * b4.y;
        acc[u][2] += av[u] * b4.z; acc[u][3] += av[u] * b4.w;
      }
    }
    __syncthreads();
  }

#pragma unroll
  for (int ri = 0; ri < 4; ++ri) {
    int r = rowBase + ty * 4 + ri;
#pragma unroll
    for (int ci = 0; ci < 4; ++ci) {
      int c = colBase + tx * 4 + ci;
      float val = acc[ri][ci];
      if (MODE == 0) {
        int b = r >> 11, i = r & 2047, h = c >> 6, d = c & 63;
        Ck[(((size_t)(b * NHEAD + h)) * SEQ_N + i) * DHEAD + d] =
            f2bf(val * SCALE_F);
      } else if (MODE == 1) {
        if (c < DHEAD) {
          Ck[(size_t)r * DHEAD + c] = f2bf(val);
        } else {
          int b = r >> 11, i = r & 2047, d = c - DHEAD;
          Cv[((size_t)b * DHEAD + d) * SEQ_N + i] = f2bf(val);
        }
      } else {
        Cf[(size_t)r * 512 + c] = val + bias[c];
      }
    }
  }
}

// ---------------------------------------------------------------------------
// Memory attention: one wave per (b,h,i) row. 33 keys (null + 32 mem keys).
// q is bf16 and pre-scaled by SCALE, so no extra scale here.
//
// Cooperative layout (all 64 lanes active, coalesced 256B segments):
//   t = lane & 15  -> owns depth slice d = t*4 .. t*4+3
//   g = lane >> 4  -> owns keys j with j % 4 == g   (8 keys per group)
// K phase: 8 wave-loads, each touching 4 contiguous 256B chunks.
// Dots reduced across the 16-lane group (shfl_xor 1,2,4,8) -> every lane of
// group g holds sim[4i+g] for i=0..7 in registers.
// Softmax: per-lane max/sum over 8 regs, cross-group combine via shfl_xor 16,32
// (within-group values identical, so each j is counted exactly once).
// V phase: same access pattern; partial float4 accumulators reduced across
// groups; lanes 0..15 store the 64-float output row.
// ---------------------------------------------------------------------------
__global__ __launch_bounds__(256) void mem_attn_kernel(
    const unsigned short* __restrict__ qb, const float* __restrict__ mem_kv,
    const int* __restrict__ mem_mask, const float* __restrict__ null_k,
    const float* __restrict__ null_v, float* __restrict__ mem_out) {
  const int w = threadIdx.x >> 6;
  const int lane = threadIdx.x & 63;
  const int row = blockIdx.x * 4 + w;  // (b*H + h)*N + i
  const int g = lane >> 4;             // key-group 0..3
  const int t = lane & 15;             // depth slot 0..15

  const float* mk = mem_kv + (size_t)row * (NMEM * 2 * DHEAD);

  // ---- issue all global loads up front (latency hides under softmax) ----
  ushort4 qu = *(const ushort4*)(qb + (size_t)row * DHEAD + t * 4);
  float4 nk4 = *(const float4*)(null_k + t * 4);
  float4 nv4 = *(const float4*)(null_v + t * 4);
  int mymask = (lane < NMEM) ? mem_mask[(size_t)row * NMEM + lane] : 1;

  float4 k4[8], v4[8];
#pragma unroll
  for (int i = 0; i < 8; ++i) {
    const float* kj = mk + (size_t)(i * 4 + g) * (2 * DHEAD);
    k4[i] = *(const float4*)(kj + t * 4);
    v4[i] = *(const float4*)(kj + DHEAD + t * 4);
  }

  const float q0 = bf2f(qu.x), q1 = bf2f(qu.y);
  const float q2 = bf2f(qu.z), q3 = bf2f(qu.w);

  // ---- null key sim (same in every lane after 16-lane reduce) ----
  float nsim = q0 * nk4.x + q1 * nk4.y + q2 * nk4.z + q3 * nk4.w;
  nsim += __shfl_xor(nsim, 1); nsim += __shfl_xor(nsim, 2);
  nsim += __shfl_xor(nsim, 4); nsim += __shfl_xor(nsim, 8);

  // ---- sims for my 8 keys ----
  float s[8];
#pragma unroll
  for (int i = 0; i < 8; ++i) {
    float sv = q0 * k4[i].x + q1 * k4[i].y + q2 * k4[i].z + q3 * k4[i].w;
    sv += __shfl_xor(sv, 1); sv += __shfl_xor(sv, 2);
    sv += __shfl_xor(sv, 4); sv += __shfl_xor(sv, 8);
    int mj = __shfl(mymask, i * 4 + g);
    s[i] = (mj == 0) ? NEG_INF : sv;
  }

  // ---- softmax over 33 entries, fully in registers ----
  float mloc = nsim;
#pragma unroll
  for (int i = 0; i < 8; ++i) mloc = fmaxf(mloc, s[i]);
  mloc = fmaxf(mloc, __shfl_xor(mloc, 16));
  mloc = fmaxf(mloc, __shfl_xor(mloc, 32));  // global max m in all lanes

  float p[8];
  float psum = 0.f;
#pragma unroll
  for (int i = 0; i < 8; ++i) { p[i] = __expf(s[i] - mloc); psum += p[i]; }
  psum += __shfl_xor(psum, 16);
  psum += __shfl_xor(psum, 32);              // sum over all 32 keys
  const float pn = __expf(nsim - mloc);
  const float linv = 1.f / (pn + psum);

  // ---- O = sum_j p_j * v_j  (group-partial, then cross-group reduce) ----
  float ax = 0.f, ay = 0.f, az = 0.f, aw = 0.f;
#pragma unroll
  for (int i = 0; i < 8; ++i) {
    float pj = p[i] * linv;
    ax += pj * v4[i].x; ay += pj * v4[i].y;
    az += pj * v4[i].z; aw += pj * v4[i].w;
  }
  ax += __shfl_xor(ax, 16); ay += __shfl_xor(ay, 16);
  az += __shfl_xor(az, 16); aw += __shfl_xor(aw, 16);
  ax += __shfl_xor(ax, 32); ay += __shfl_xor(ay, 32);
  az += __shfl_xor(az, 32); aw += __shfl_xor(aw, 32);

  const float pnl = pn * linv;
  ax += pnl * nv4.x; ay += pnl * nv4.y;
  az += pnl * nv4.z; aw += pnl * nv4.w;

  if (g == 0) {
    float4 o = {ax, ay, az, aw};
    *(float4*)(mem_out + (size_t)row * DHEAD + t * 4) = o;
  }
}

// ---------------------------------------------------------------------------
// Causal local attention, MFMA bf16 flash-style + gated combine with mem.
// Block = 256 thr = 4 waves; 64 query rows per block (16 per wave); K-tiles
// of 64 keys. Q pre-scaled bf16. P round-trips through LDS (C-layout ->
// A-layout). V staged transposed so B-frags are contiguous b128 reads.
// MFMA layouts (gfx950, 16x16x32): A[m=lane&15][k=quad*8+j],
// B[k=quad*8+j][n=lane&15], C/D col=lane&15 row=quad*4+reg.
// ---------------------------------------------------------------------------
__global__ __launch_bounds__(256) void local_attn_mfma(
    const unsigned short* __restrict__ qb, const unsigned short* __restrict__ kb,
    const unsigned short* __restrict__ vtb, const float* __restrict__ mem_o,
    const float* __restrict__ gate, float* __restrict__ comb) {
  __shared__ unsigned short sK[64 * LDK];   // [key][depth]
  __shared__ unsigned short sV[64 * LDK];   // [d][key]  (transposed V)
  __shared__ unsigned short sP[4 * 16 * LDK];  // per-wave 16x64 P tile

  const int tid = threadIdx.x;
  const int w = tid >> 6, lane = tid & 63;
  const int m = lane & 15, quad = lane >> 4;
  const int bid = blockIdx.x;
  const int qt = 31 - (bid >> 4);          // heavy q-tiles first
  const int bh = bid & 15;
  const int b = bh >> 3, h = bh & 7;
  const int qbase = qt * 64;

  // Q A-fragments (persist for whole block)
  const unsigned short* qp =
      qb + (((size_t)bh * SEQ_N + qbase + w * 16 + m) * DHEAD) + quad * 8;
  const bf16x8 aq0 = *(const bf16x8*)qp;
  const bf16x8 aq1 = *(const bf16x8*)(qp + 32);

  f32x4 acc[4] = {};                        // [dblk], rows = quad*4+reg
  float mrow[4], lrow[4];
#pragma unroll
  for (int r = 0; r < 4; ++r) { mrow[r] = NEG_INF; lrow[r] = 0.f; }

  unsigned short* sPw = &sP[w * 16 * LDK];

  for (int kt = 0; kt <= qt; ++kt) {
    const int kbase0 = kt * 64;
    __syncthreads();
#pragma unroll
    for (int it = 0; it < 2; ++it) {
      int idx = tid + it * 256;             // 0..511
      int row = idx >> 3, ch = idx & 7;
      *(uint4*)&sK[row * LDK + ch * 8] =
          *(const uint4*)(kb + ((size_t)b * SEQ_N + kbase0 + row) * DHEAD + ch * 8);
      *(uint4*)&sV[row * LDK + ch * 8] =
          *(const uint4*)(vtb + ((size_t)b * DHEAD + row) * SEQ_N + kbase0 + ch * 8);
    }
    __syncthreads();

    // ---- S = Qs · K^T  (16 x 64 per wave) ----
    f32x4 s[4] = {};
#pragma unroll
    for (int nb = 0; nb < 4; ++nb) {
      bf16x8 bk0 = *(const bf16x8*)&sK[(nb * 16 + m) * LDK + quad * 8];
      bf16x8 bk1 = *(const bf16x8*)&sK[(nb * 16 + m) * LDK + 32 + quad * 8];
      s[nb] = __builtin_amdgcn_mfma_f32_16x16x32_bf16(aq0, bk0, s[nb], 0, 0, 0);
      s[nb] = __builtin_amdgcn_mfma_f32_16x16x32_bf16(aq1, bk1, s[nb], 0, 0, 0);
    }

    if (kt == qt) {                         // diagonal tile: causal mask
      int irow0 = w * 16 + quad * 4;
#pragma unroll
      for (int nb = 0; nb < 4; ++nb) {
        int j = nb * 16 + m;
#pragma unroll
        for (int r = 0; r < 4; ++r)
          if (j > irow0 + r) s[nb][r] = NEG_INF;
      }
    }

    // ---- online softmax (per query row; rows live in 16-lane quads) ----
#pragma unroll
    for (int r = 0; r < 4; ++r) {
      float mx = fmaxf(fmaxf(s[0][r], s[1][r]), fmaxf(s[2][r], s[3][r]));
      mx = fmaxf(mx, __shfl_xor(mx, 1));
      mx = fmaxf(mx, __shfl_xor(mx, 2));
      mx = fmaxf(mx, __shfl_xor(mx, 4));
      mx = fmaxf(mx, __shfl_xor(mx, 8));
      float mnew = fmaxf(mrow[r], mx);
      float alpha = __expf(mrow[r] - mnew);
      mrow[r] = mnew;
      float rs = 0.f;
#pragma unroll
      for (int nb = 0; nb < 4; ++nb) {
        float p = __expf(s[nb][r] - mnew);
        s[nb][r] = p;
        rs += p;
      }
      rs += __shfl_xor(rs, 1); rs += __shfl_xor(rs, 2);
      rs += __shfl_xor(rs, 4); rs += __shfl_xor(rs, 8);
      lrow[r] = lrow[r] * alpha + rs;
#pragma unroll
      for (int db = 0; db < 4; ++db) acc[db][r] *= alpha;
    }

    // ---- P (C-layout) -> LDS -> A-layout ----
#pragma unroll
    for (int nb = 0; nb < 4; ++nb)
#pragma unroll
      for (int r = 0; r < 4; ++r)
        sPw[(quad * 4 + r) * LDK + nb * 16 + m] = f2bf(s[nb][r]);

    bf16x8 ap0 = *(const bf16x8*)&sPw[m * LDK + quad * 8];
    bf16x8 ap1 = *(const bf16x8*)&sPw[m * LDK + 32 + quad * 8];

    // ---- O += P · V ----
#pragma unroll
    for (int db = 0; db < 4; ++db) {
      bf16x8 bv0 = *(const bf16x8*)&sV[(db * 16 + m) * LDK + quad * 8];
      bf16x8 bv1 = *(const bf16x8*)&sV[(db * 16 + m) * LDK + 32 + quad * 8];
      acc[db] = __builtin_amdgcn_mfma_f32_16x16x32_bf16(ap0, bv0, acc[db], 0, 0, 0);
      acc[db] = __builtin_amdgcn_mfma_f32_16x16x32_bf16(ap1, bv1, acc[db], 0, 0, 0);
    }
  }

  // ---- epilogue: normalize, gate-combine with memory attention ----
  const float g = 1.f / (1.f + __expf(-gate[h]));
#pragma unroll
  for (int r = 0; r < 4; ++r) {
    int i = qbase + w * 16 + quad * 4 + r;
    float invl = 1.f / lrow[r];
#pragma unroll
    for (int db = 0; db < 4; ++db) {
      int d = db * 16 + m;
      float localv = acc[db][r] * invl;
      float memv = mem_o[((size_t)bh * SEQ_N + i) * DHEAD + d];
      comb[((size_t)(b * SEQ_N + i)) * 512 + h * DHEAD + d] =
          g * localv + (1.f - g) * memv;
    }
  }
}

// ---------------------------------------------------------------------------
extern "C" void kernel_launch(void* const* d_in, const int* in_sizes, int n_in,
                              void* d_out, int out_size, void* d_ws, size_t ws_size,
                              hipStream_t stream) {
  const float* x        = (const float*)d_in[0];
  const float* mem_kv   = (const float*)d_in[1];
  const int*   mem_mask = (const int*)d_in[2];
  const float* Wq       = (const float*)d_in[3];
  const float* Wkv      = (const float*)d_in[4];
  const float* Wo       = (const float*)d_in[5];
  const float* bo       = (const float*)d_in[6];
  const float* null_k   = (const float*)d_in[7];
  const float* null_v   = (const float*)d_in[8];
  const float* gate     = (const float*)d_in[9];
  float* out = (float*)d_out;

  // workspace layout (16B-aligned chunks)
  unsigned short* qb  = (unsigned short*)d_ws;          // (B,H,N,DH) bf16: 4 MB
  unsigned short* kbw = qb + 2097152;                   // (B,N,DH)   bf16: 512 KB
  unsigned short* vtb = kbw + 262144;                   // (B,DH,N)   bf16: 512 KB
  float* mem_o = (float*)(vtb + 262144);                // (B,H,N,DH) f32:  8 MB
  float* comb  = mem_o + 2097152;                       // (B,N,512)  f32:  8 MB

  dim3 blk(256);
  // QKV projections (f32 compute, bf16 outputs for attention)
  gemm64<0><<<dim3(64, 8), blk, 0, stream>>>(x, Wq, nullptr, qb, nullptr, nullptr, 512, 512);
  gemm64<1><<<dim3(64, 2), blk, 0, stream>>>(x, Wkv, nullptr, kbw, vtb, nullptr, 512, 128);
  // memory attention (HBM-bound: streams 536 MB of mem_kv)
  mem_attn_kernel<<<8192, blk, 0, stream>>>(qb, mem_kv, mem_mask, null_k, null_v, mem_o);
  // causal local attention (MFMA) + gated combine
  local_attn_mfma<<<512, blk, 0, stream>>>(qb, kbw, vtb, mem_o, gate, comb);
  // output projection + bias (f32)
  gemm64<2><<<dim3(64, 8), blk, 0, stream>>>(comb, Wo, out, nullptr, nullptr, bo, 512, 512);
}

// Round 3
// 846.509 us; speedup vs baseline: 1.0495x; 1.0495x over previous
//
#include <hip/hip_runtime.h>
#include <cstddef>
#include <cstdint>

// Problem constants: B=2, N=2048, DIM=512, H=8, DH=64, K=32, SCALE=1/8
#define SEQ_N  2048
#define NHEAD  8
#define DHEAD  64
#define NMEM   32
#define SCALE_F 0.125f
#define NEG_INF -3.0e38f
#define LDK 72  // padded LDS row stride (ushort units) for 64-wide bf16 tiles

typedef short bf16x8 __attribute__((ext_vector_type(8)));
typedef float f32x4  __attribute__((ext_vector_type(4)));

__device__ __forceinline__ unsigned short f2bf(float f) {
  union { float f; uint32_t u; } v; v.f = f;
  uint32_t u = v.u;
  return (unsigned short)((u + 0x7fffu + ((u >> 16) & 1u)) >> 16);  // RNE
}
__device__ __forceinline__ float bf2f(unsigned short us) {
  union { uint32_t u; float f; } v; v.u = ((uint32_t)us) << 16; return v.f;
}

// ---------------------------------------------------------------------------
// Fused QKV projection: 64x64-tile f32 GEMM, 256 threads, 4x4 microtile.
// grid = (64, 10): blockIdx.y < 8  -> Wq tile  (cols h*64+d), bf16 q * SCALE
//                  blockIdx.y >= 8 -> Wkv tile (cols 0..127): k -> kb,
//                                    v -> vtb (transposed (b,d,i))
// ---------------------------------------------------------------------------
__global__ __launch_bounds__(256) void gemm_qkv(
    const float* __restrict__ A, const float* __restrict__ Wq,
    const float* __restrict__ Wkv, unsigned short* __restrict__ qbo,
    unsigned short* __restrict__ kbo, unsigned short* __restrict__ vto) {
  __shared__ float sA[64][17];
  __shared__ float sB[16][64];
  const int tid = threadIdx.x;
  const int tx = tid & 15, ty = tid >> 4;
  const int rowBase = blockIdx.x * 64;
  const int by = blockIdx.y;
  const bool isQ = (by < 8);
  const float* __restrict__ Bw = isQ ? Wq : Wkv;
  const int Ncols = isQ ? 512 : 128;
  const int colBase = (isQ ? by : (by - 8)) * 64;
  float acc[4][4] = {};

  for (int k0 = 0; k0 < 512; k0 += 16) {
    {
      int r = tid >> 2, ks = (tid & 3) * 4;
      float4 a4 = *(const float4*)(A + (size_t)(rowBase + r) * 512 + k0 + ks);
      sA[r][ks + 0] = a4.x; sA[r][ks + 1] = a4.y;
      sA[r][ks + 2] = a4.z; sA[r][ks + 3] = a4.w;
    }
#pragma unroll
    for (int it = 0; it < 4; ++it) {
      int kk = (tid >> 6) + it * 4, c = tid & 63;
      sB[kk][c] = Bw[(size_t)(k0 + kk) * Ncols + colBase + c];
    }
    __syncthreads();
#pragma unroll
    for (int kk = 0; kk < 16; ++kk) {
      float av[4];
#pragma unroll
      for (int u = 0; u < 4; ++u) av[u] = sA[ty * 4 + u][kk];
      float4 b4 = *(const float4*)&sB[kk][tx * 4];
#pragma unroll
      for (int u = 0; u < 4; ++u) {
        acc[u][0] += av[u] * b4.x; acc[u][1] += av[u] * b4.y;
        acc[u][2] += av[u] * b4.z; acc[u][3] += av[u] * b4.w;
      }
    }
    __syncthreads();
  }

#pragma unroll
  for (int ri = 0; ri < 4; ++ri) {
    int r = rowBase + ty * 4 + ri;
#pragma unroll
    for (int ci = 0; ci < 4; ++ci) {
      int c = colBase + tx * 4 + ci;
      float val = acc[ri][ci];
      int b = r >> 11, i = r & 2047;
      if (isQ) {
        int h = c >> 6, d = c & 63;
        qbo[(((size_t)(b * NHEAD + h)) * SEQ_N + i) * DHEAD + d] =
            f2bf(val * SCALE_F);
      } else {
        if (c < DHEAD) {
          kbo[(size_t)r * DHEAD + c] = f2bf(val);
        } else {
          int d = c - DHEAD;
          vto[((size_t)b * DHEAD + d) * SEQ_N + i] = f2bf(val);
        }
      }
    }
  }
}

// ---------------------------------------------------------------------------
// Output projection: comb @ Wo + bo (f32), 64x64 tiles.
// ---------------------------------------------------------------------------
__global__ __launch_bounds__(256) void gemm_out(
    const float* __restrict__ A, const float* __restrict__ Bw,
    float* __restrict__ Cf, const float* __restrict__ bias) {
  __shared__ float sA[64][17];
  __shared__ float sB[16][64];
  const int tid = threadIdx.x;
  const int tx = tid & 15, ty = tid >> 4;
  const int rowBase = blockIdx.x * 64, colBase = blockIdx.y * 64;
  float acc[4][4] = {};

  for (int k0 = 0; k0 < 512; k0 += 16) {
    {
      int r = tid >> 2, ks = (tid & 3) * 4;
      float4 a4 = *(const float4*)(A + (size_t)(rowBase + r) * 512 + k0 + ks);
      sA[r][ks + 0] = a4.x; sA[r][ks + 1] = a4.y;
      sA[r][ks + 2] = a4.z; sA[r][ks + 3] = a4.w;
    }
#pragma unroll
    for (int it = 0; it < 4; ++it) {
      int kk = (tid >> 6) + it * 4, c = tid & 63;
      sB[kk][c] = Bw[(size_t)(k0 + kk) * 512 + colBase + c];
    }
    __syncthreads();
#pragma unroll
    for (int kk = 0; kk < 16; ++kk) {
      float av[4];
#pragma unroll
      for (int u = 0; u < 4; ++u) av[u] = sA[ty * 4 + u][kk];
      float4 b4 = *(const float4*)&sB[kk][tx * 4];
#pragma unroll
      for (int u = 0; u < 4; ++u) {
        acc[u][0] += av[u] * b4.x; acc[u][1] += av[u] * b4.y;
        acc[u][2] += av[u] * b4.z; acc[u][3] += av[u] * b4.w;
      }
    }
    __syncthreads();
  }

#pragma unroll
  for (int ri = 0; ri < 4; ++ri) {
    int r = rowBase + ty * 4 + ri;
#pragma unroll
    for (int ci = 0; ci < 4; ++ci) {
      int c = colBase + tx * 4 + ci;
      Cf[(size_t)r * 512 + c] = acc[ri][ci] + bias[c];
    }
  }
}

// ---------------------------------------------------------------------------
// Fused attention: memory attention (33 keys) + causal local MFMA attention
// + gated combine. Block = 256 thr = 4 waves; 64 query rows per block.
//
// Phase 0 (per wave, rows w*16+rr): cooperative mem-attention.
//   t = lane&15 owns depth d=t*4..t*4+3; g = lane>>4 owns keys j%4==g.
//   8 coalesced wave-loads for K, 8 for V; dots reduced via shfl_xor(1,2,4,8);
//   softmax in registers, cross-group via shfl_xor(16,32); result -> sM (LDS).
// Phase 1: flash-style causal local attention (MFMA bf16), as before.
// Epilogue: comb = sigmoid(gate)*local + (1-sig)*sM.
// ---------------------------------------------------------------------------
__global__ __launch_bounds__(256) void attn_fused(
    const unsigned short* __restrict__ qb, const unsigned short* __restrict__ kb,
    const unsigned short* __restrict__ vtb, const float* __restrict__ mem_kv,
    const int* __restrict__ mem_mask, const float* __restrict__ null_k,
    const float* __restrict__ null_v, const float* __restrict__ gate,
    float* __restrict__ comb) {
  __shared__ unsigned short sK[64 * LDK];   // [key][depth]
  __shared__ unsigned short sV[64 * LDK];   // [d][key]  (transposed V)
  __shared__ unsigned short sP[4 * 16 * LDK];  // per-wave 16x64 P tile
  __shared__ float sM[64][64];              // mem-attention output rows

  const int tid = threadIdx.x;
  const int w = tid >> 6, lane = tid & 63;
  const int m = lane & 15, quad = lane >> 4;
  const int bid = blockIdx.x;
  const int qt = 31 - (bid >> 4);          // heavy q-tiles first
  const int bh = bid & 15;
  const int b = bh >> 3, h = bh & 7;
  const int qbase = qt * 64;

  // ---- Phase 0: memory attention for this block's 64 rows ----
  {
    const int g = lane >> 4;             // key-group 0..3
    const int t = lane & 15;             // depth slot 0..15
    const float4 nk4 = *(const float4*)(null_k + t * 4);
    const float4 nv4 = *(const float4*)(null_v + t * 4);

    for (int rr = 0; rr < 16; ++rr) {
      const size_t rowg = (size_t)bh * SEQ_N + qbase + w * 16 + rr;
      const float* mk = mem_kv + rowg * (NMEM * 2 * DHEAD);

      ushort4 qu = *(const ushort4*)(qb + rowg * DHEAD + t * 4);
      int mymask = (lane < NMEM) ? mem_mask[rowg * NMEM + lane] : 1;
      float4 k4[8], v4[8];
#pragma unroll
      for (int i = 0; i < 8; ++i) {
        const float* kj = mk + (size_t)(i * 4 + g) * (2 * DHEAD);
        k4[i] = *(const float4*)(kj + t * 4);
        v4[i] = *(const float4*)(kj + DHEAD + t * 4);
      }

      const float q0 = bf2f(qu.x), q1 = bf2f(qu.y);
      const float q2 = bf2f(qu.z), q3 = bf2f(qu.w);

      float nsim = q0 * nk4.x + q1 * nk4.y + q2 * nk4.z + q3 * nk4.w;
      nsim += __shfl_xor(nsim, 1); nsim += __shfl_xor(nsim, 2);
      nsim += __shfl_xor(nsim, 4); nsim += __shfl_xor(nsim, 8);

      float s[8];
#pragma unroll
      for (int i = 0; i < 8; ++i) {
        float sv = q0 * k4[i].x + q1 * k4[i].y + q2 * k4[i].z + q3 * k4[i].w;
        sv += __shfl_xor(sv, 1); sv += __shfl_xor(sv, 2);
        sv += __shfl_xor(sv, 4); sv += __shfl_xor(sv, 8);
        int mj = __shfl(mymask, i * 4 + g);
        s[i] = (mj == 0) ? NEG_INF : sv;
      }

      float mloc = nsim;
#pragma unroll
      for (int i = 0; i < 8; ++i) mloc = fmaxf(mloc, s[i]);
      mloc = fmaxf(mloc, __shfl_xor(mloc, 16));
      mloc = fmaxf(mloc, __shfl_xor(mloc, 32));

      float p[8];
      float psum = 0.f;
#pragma unroll
      for (int i = 0; i < 8; ++i) { p[i] = __expf(s[i] - mloc); psum += p[i]; }
      psum += __shfl_xor(psum, 16);
      psum += __shfl_xor(psum, 32);
      const float pn = __expf(nsim - mloc);
      const float linv = 1.f / (pn + psum);

      float ax = 0.f, ay = 0.f, az = 0.f, aw = 0.f;
#pragma unroll
      for (int i = 0; i < 8; ++i) {
        float pj = p[i] * linv;
        ax += pj * v4[i].x; ay += pj * v4[i].y;
        az += pj * v4[i].z; aw += pj * v4[i].w;
      }
      ax += __shfl_xor(ax, 16); ay += __shfl_xor(ay, 16);
      az += __shfl_xor(az, 16); aw += __shfl_xor(aw, 16);
      ax += __shfl_xor(ax, 32); ay += __shfl_xor(ay, 32);
      az += __shfl_xor(az, 32); aw += __shfl_xor(aw, 32);

      const float pnl = pn * linv;
      ax += pnl * nv4.x; ay += pnl * nv4.y;
      az += pnl * nv4.z; aw += pnl * nv4.w;

      if (g == 0) {
        float4 o = {ax, ay, az, aw};
        *(float4*)&sM[w * 16 + rr][t * 4] = o;   // wave-private rows
      }
    }
  }

  // ---- Phase 1: causal local attention (MFMA) ----
  const unsigned short* qp =
      qb + (((size_t)bh * SEQ_N + qbase + w * 16 + m) * DHEAD) + quad * 8;
  const bf16x8 aq0 = *(const bf16x8*)qp;
  const bf16x8 aq1 = *(const bf16x8*)(qp + 32);

  f32x4 acc[4] = {};                        // [dblk], rows = quad*4+reg
  float mrow[4], lrow[4];
#pragma unroll
  for (int r = 0; r < 4; ++r) { mrow[r] = NEG_INF; lrow[r] = 0.f; }

  unsigned short* sPw = &sP[w * 16 * LDK];

  for (int kt = 0; kt <= qt; ++kt) {
    const int kbase0 = kt * 64;
    __syncthreads();
#pragma unroll
    for (int it = 0; it < 2; ++it) {
      int idx = tid + it * 256;             // 0..511
      int row = idx >> 3, ch = idx & 7;
      *(uint4*)&sK[row * LDK + ch * 8] =
          *(const uint4*)(kb + ((size_t)b * SEQ_N + kbase0 + row) * DHEAD + ch * 8);
      *(uint4*)&sV[row * LDK + ch * 8] =
          *(const uint4*)(vtb + ((size_t)b * DHEAD + row) * SEQ_N + kbase0 + ch * 8);
    }
    __syncthreads();

    // ---- S = Qs · K^T  (16 x 64 per wave) ----
    f32x4 s[4] = {};
#pragma unroll
    for (int nb = 0; nb < 4; ++nb) {
      bf16x8 bk0 = *(const bf16x8*)&sK[(nb * 16 + m) * LDK + quad * 8];
      bf16x8 bk1 = *(const bf16x8*)&sK[(nb * 16 + m) * LDK + 32 + quad * 8];
      s[nb] = __builtin_amdgcn_mfma_f32_16x16x32_bf16(aq0, bk0, s[nb], 0, 0, 0);
      s[nb] = __builtin_amdgcn_mfma_f32_16x16x32_bf16(aq1, bk1, s[nb], 0, 0, 0);
    }

    if (kt == qt) {                         // diagonal tile: causal mask
      int irow0 = w * 16 + quad * 4;
#pragma unroll
      for (int nb = 0; nb < 4; ++nb) {
        int j = nb * 16 + m;
#pragma unroll
        for (int r = 0; r < 4; ++r)
          if (j > irow0 + r) s[nb][r] = NEG_INF;
      }
    }

    // ---- online softmax (per query row; rows live in 16-lane quads) ----
#pragma unroll
    for (int r = 0; r < 4; ++r) {
      float mx = fmaxf(fmaxf(s[0][r], s[1][r]), fmaxf(s[2][r], s[3][r]));
      mx = fmaxf(mx, __shfl_xor(mx, 1));
      mx = fmaxf(mx, __shfl_xor(mx, 2));
      mx = fmaxf(mx, __shfl_xor(mx, 4));
      mx = fmaxf(mx, __shfl_xor(mx, 8));
      float mnew = fmaxf(mrow[r], mx);
      float alpha = __expf(mrow[r] - mnew);
      mrow[r] = mnew;
      float rs = 0.f;
#pragma unroll
      for (int nb = 0; nb < 4; ++nb) {
        float p = __expf(s[nb][r] - mnew);
        s[nb][r] = p;
        rs += p;
      }
      rs += __shfl_xor(rs, 1); rs += __shfl_xor(rs, 2);
      rs += __shfl_xor(rs, 4); rs += __shfl_xor(rs, 8);
      lrow[r] = lrow[r] * alpha + rs;
#pragma unroll
      for (int db = 0; db < 4; ++db) acc[db][r] *= alpha;
    }

    // ---- P (C-layout) -> LDS -> A-layout ----
#pragma unroll
    for (int nb = 0; nb < 4; ++nb)
#pragma unroll
      for (int r = 0; r < 4; ++r)
        sPw[(quad * 4 + r) * LDK + nb * 16 + m] = f2bf(s[nb][r]);

    bf16x8 ap0 = *(const bf16x8*)&sPw[m * LDK + quad * 8];
    bf16x8 ap1 = *(const bf16x8*)&sPw[m * LDK + 32 + quad * 8];

    // ---- O += P · V ----
#pragma unroll
    for (int db = 0; db < 4; ++db) {
      bf16x8 bv0 = *(const bf16x8*)&sV[(db * 16 + m) * LDK + quad * 8];
      bf16x8 bv1 = *(const bf16x8*)&sV[(db * 16 + m) * LDK + 32 + quad * 8];
      acc[db] = __builtin_amdgcn_mfma_f32_16x16x32_bf16(ap0, bv0, acc[db], 0, 0, 0);
      acc[db] = __builtin_amdgcn_mfma_f32_16x16x32_bf16(ap1, bv1, acc[db], 0, 0, 0);
    }
  }

  // ---- epilogue: normalize, gate-combine with memory attention ----
  const float gh = 1.f / (1.f + __expf(-gate[h]));
#pragma unroll
  for (int r = 0; r < 4; ++r) {
    int i = qbase + w * 16 + quad * 4 + r;
    float invl = 1.f / lrow[r];
#pragma unroll
    for (int db = 0; db < 4; ++db) {
      int d = db * 16 + m;
      float localv = acc[db][r] * invl;
      float memv = sM[w * 16 + quad * 4 + r][d];
      comb[((size_t)(b * SEQ_N + i)) * 512 + h * DHEAD + d] =
          gh * localv + (1.f - gh) * memv;
    }
  }
}

// ---------------------------------------------------------------------------
extern "C" void kernel_launch(void* const* d_in, const int* in_sizes, int n_in,
                              void* d_out, int out_size, void* d_ws, size_t ws_size,
                              hipStream_t stream) {
  const float* x        = (const float*)d_in[0];
  const float* mem_kv   = (const float*)d_in[1];
  const int*   mem_mask = (const int*)d_in[2];
  const float* Wq       = (const float*)d_in[3];
  const float* Wkv      = (const float*)d_in[4];
  const float* Wo       = (const float*)d_in[5];
  const float* bo       = (const float*)d_in[6];
  const float* null_k   = (const float*)d_in[7];
  const float* null_v   = (const float*)d_in[8];
  const float* gate     = (const float*)d_in[9];
  float* out = (float*)d_out;

  // workspace layout (16B-aligned chunks)
  unsigned short* qb  = (unsigned short*)d_ws;          // (B,H,N,DH) bf16: 4 MB
  unsigned short* kbw = qb + 2097152;                   // (B,N,DH)   bf16: 512 KB
  unsigned short* vtb = kbw + 262144;                   // (B,DH,N)   bf16: 512 KB
  float* comb  = (float*)(vtb + 262144);                // (B,N,512)  f32:  8 MB

  dim3 blk(256);
  // fused QKV projections (f32 compute, bf16 outputs for attention)
  gemm_qkv<<<dim3(64, 10), blk, 0, stream>>>(x, Wq, Wkv, qb, kbw, vtb);
  // fused memory + causal local attention + gated combine
  attn_fused<<<512, blk, 0, stream>>>(qb, kbw, vtb, mem_kv, mem_mask,
                                      null_k, null_v, gate, comb);
  // output projection + bias (f32)
  gemm_out<<<dim3(64, 8), blk, 0, stream>>>(comb, Wo, out, bo);
}